// Round 12
// baseline (1173.203 us; speedup 1.0000x reference)
//
#include <hip/hip_runtime.h>
#include <hip/hip_bf16.h>
#include <cstdint>

#define LH   50
#define PP   30
#define NAG  2048
#define NHID 128
#define EHID 256
#define ADIM 64
#define CNND 2048

typedef __attribute__((ext_vector_type(8))) short bf16x8;
typedef __attribute__((ext_vector_type(4))) float f32x4;

// ---- workspace layout (float slots) -----------------------------------------
// W image: [c=8][s=4][j=1024][i=8] bf16  (k = c*32 + s*8 + i)
enum : int {
  WS_WT  = 0,        // 131072 fl (512KB)
  WS_WHT = 131072,   // bf16 WhtT[512][128] -> 32768
  WS_WFN = 163840,   // wf0[1024] wf1[1024]
  WS_BFN = 165888,   // wb[1024]
  WS_WFT = 166912,   // 2*512
  WS_BFT = 167936,   // 512
  WS_TH  = 168448,   // 128
  WS_TC  = 168576,   // 128
  WS_W49 = 168704,   // 2048
  WS_CN  = 170752,   // 1 (+3 pad)
  WS_Z   = 170756,   // 30*2048*2
  WS_FLG = 293636,   // 256 ints (pair sync flags)
  WS_HG  = 293892,   // bf16 H exchange buffer [2048][256] -> 131072 fl
  WS_END = 424964
};

__device__ __forceinline__ float sigf(float x){ return 1.0f/(1.0f + __expf(-x)); }
__device__ __forceinline__ float tanhfast(float x){
  x = fminf(15.0f, fmaxf(-15.0f, x));
  float e = __expf(2.0f*x);
  return (e - 1.0f)/(e + 1.0f);
}
__device__ __forceinline__ float bfs(short s){
  return __uint_as_float(((unsigned)(unsigned short)s) << 16);
}

// ---- prep: W image [c][s][j][8], WhtT, folds, flag zero ----------------------
__global__ void k_prep(const float* __restrict__ Whhn, const float* __restrict__ Whht,
                       const float* __restrict__ Wnemb, const float* __restrict__ bnemb,
                       const float* __restrict__ Wihn,  const float* __restrict__ bihn,
                       const float* __restrict__ bhhn,
                       const float* __restrict__ Wtemb, const float* __restrict__ btemb,
                       const float* __restrict__ Wiht,  const float* __restrict__ biht,
                       const float* __restrict__ bhht,
                       float* __restrict__ ws)
{
  const int b = blockIdx.x, tid = threadIdx.x;
  if (b < 256){
    __shared__ float t[32][33];
    __hip_bfloat16* WT = (__hip_bfloat16*)(ws + WS_WT);
    const int tx = tid & 31, ty = tid >> 5;     // ty in [0,8)
    const int j0 = (b & 31) << 5;
    const int c  = b >> 5;                      // k-chunk 0..7
    const int e0 = c << 5;
    #pragma unroll
    for (int r = 0; r < 4; ++r)
      t[ty + 8*r][tx] = Whhn[(e0 + ty + 8*r)*1024 + j0 + tx];
    __syncthreads();
    #pragma unroll
    for (int r = 0; r < 4; ++r)
      WT[c*32768 + r*8192 + (j0 + tx)*8 + ty] = __float2bfloat16(t[ty + 8*r][tx]);
  } else {
    for (int j = tid; j < 1024; j += 256){
      float a0=0.f, a1=0.f, ab=0.f;
      for (int k=0;k<64;k++){
        const float w = Wihn[k*1024 + j];
        a0 += Wnemb[k]*w; a1 += Wnemb[64+k]*w; ab += bnemb[k]*w;
      }
      ws[WS_WFN + j]        = a0;
      ws[WS_WFN + 1024 + j] = a1;
      ws[WS_BFN + j]        = ab + bihn[j] + bhhn[j];
    }
    for (int j = tid; j < 512; j += 256){
      float a0=0.f, a1=0.f, ab=0.f;
      for (int k=0;k<64;k++){
        const float w = Wiht[k*512 + j];
        a0 += Wtemb[k]*w; a1 += Wtemb[64+k]*w; ab += btemb[k]*w;
      }
      ws[WS_WFT + j]       = a0;
      ws[WS_WFT + 512 + j] = a1;
      ws[WS_BFT + j]       = ab + biht[j] + bhht[j];
    }
    __hip_bfloat16* WTt = (__hip_bfloat16*)(ws + WS_WHT);
    for (int j = tid; j < 512; j += 256)
      for (int k = 0; k < 128; ++k)
        WTt[j*128 + k] = __float2bfloat16(Whht[k*512 + j]);
    // zero pair flags (re-run each launch -> replay-safe)
    if (tid < 256) ((int*)(ws + WS_FLG))[tid] = 0;
  }
}

// ---- Phase A ------------------------------------------------------------------
// b==0: target obs chain (VGPR-cached WhtT). b==1: w49 precompute.
// b>=2: pair blocks. pb = b-2 in [0,256): agrp = pb&127 (16 agents),
//   h = pb>>7 (e-half), partner = pb^128 (same XCD: 128%8==0).
//   W slice (512 j x 256 k = 256KB) FULLY resident: k-chunks 0..3 in VGPR
//   (128 regs), k-chunks 4..7 in LDS (128KB, lane-linear tiles). Per step:
//   MFMA -> gates(own half) -> H-half exchange via WS_HG + flag handshake.
// dyn LDS: ldsW 131072 | Hl 8448 | relS 6400 | vS 2048 | zS 3840 | wfL 6144
__global__ __launch_bounds__(256, 1) void k_phaseA(
    const float* __restrict__ nh0, const float* __restrict__ nc0,
    const float* __restrict__ nrel, const int* __restrict__ nhist,
    const float* __restrict__ Wpred,
    const float* __restrict__ trel, const int* __restrict__ thsp,
    const float* __restrict__ Whht, const float* __restrict__ th0,
    const float* __restrict__ tc0,
    const float* __restrict__ tpos, const float* __restrict__ npos,
    const float* __restrict__ Wtatt, const float* __restrict__ btatt,
    const float* __restrict__ Wnatt, const float* __restrict__ bnatt,
    float* __restrict__ ws)
{
  extern __shared__ char smem[];
  const int b = blockIdx.x, tid = threadIdx.x;
  const int wv = tid >> 6, lane = tid & 63;
  const int lhi = lane >> 4, llo = lane & 15;

  if (b >= 2){
    const int pb = b - 2;
    const int agrp = pb & 127;
    const int h    = pb >> 7;
    const int pidx = pb ^ 128;
    const int n0   = agrp << 4;
    int* flg = (int*)(ws + WS_FLG);
    short* HgS = (short*)(ws + WS_HG);

    short* ldsW = (short*)smem;                    // 131072 B
    short* Hl   = (short*)(smem + 131072);         // [16][264] shorts
    float* relS = (float*)(smem + 139520);         // 1600 fl
    float* vS   = (float*)(smem + 145920);         // 512 fl
    float* zS   = (float*)(smem + 147968);         // 960 fl
    float* wfL  = (float*)(smem + 151808);         // 1536 fl
    const short* wt = (const short*)(ws + WS_WT);

    // ---- one-time: VGPR W (k-chunks 0..3) ----
    bf16x8 wreg[4][4][2];    // [c][g][t] -> 128 VGPR
    #pragma unroll
    for (int c = 0; c < 4; ++c)
      #pragma unroll
      for (int g = 0; g < 4; ++g)
        #pragma unroll
        for (int t = 0; t < 2; ++t){
          const int j = g*256 + h*128 + (wv<<5) + t*16 + llo;
          wreg[c][g][t] = *(const bf16x8*)(wt + c*32768 + lhi*8192 + j*8);
        }
    // ---- one-time: LDS W (k-chunks 4..7), lane-linear tiles ----
    // layout: u = c*2048 + wv*512 + g*128 + t*64 + lane  (8 shorts per u)
    for (int u = tid; u < 8192; u += 256){
      const int lane_u = u & 63;
      const int t_u  = (u >> 6) & 1;
      const int g_u  = (u >> 7) & 3;
      const int wv_u = (u >> 9) & 3;
      const int c_u  = (u >> 11) & 3;
      const int llo_u = lane_u & 15, lhi_u = lane_u >> 4;
      const int j_u = g_u*256 + h*128 + wv_u*32 + t_u*16 + llo_u;
      *(uint4*)(ldsW + u*8) = *(const uint4*)(wt + (4+c_u)*32768 + lhi_u*8192 + j_u*8);
    }
    // folded gate consts for own j-set
    for (int i = tid; i < 512; i += 256){
      const int llo_i = i & 15, t_i = (i >> 4) & 1, g_i = (i >> 5) & 3, wv_i = (i >> 7) & 3;
      const int j = g_i*256 + h*128 + wv_i*32 + t_i*16 + llo_i;
      wfL[i]        = ws[WS_WFN + j];
      wfL[512 + i]  = ws[WS_WFN + 1024 + j];
      wfL[1024 + i] = ws[WS_BFN + j];
    }
    for (int i = tid; i < 1600; i += 256){
      const int a = i / 100, r = i % 100;
      relS[a*100 + r] = nrel[(n0 + a)*100 + r];
    }
    vS[2*tid]   = Wpred[2*(NHID + CNND + tid)];
    vS[2*tid+1] = Wpred[2*(NHID + CNND + tid) + 1];
    for (int i = tid; i < 4096; i += 256){
      const int a = i >> 8, e = i & 255;
      ((__hip_bfloat16*)Hl)[a*264 + e] = __float2bfloat16(nh0[e]);
    }
    float C[4][2];
    #pragma unroll
    for (int r = 0; r < 4; ++r)
      #pragma unroll
      for (int t = 0; t < 2; ++t)
        C[r][t] = nc0[h*128 + (wv<<5) + t*16 + llo];
    int nh4[4];
    #pragma unroll
    for (int r = 0; r < 4; ++r) nh4[r] = nhist[n0 + lhi*4 + r];
    int nhmax = 0;
    for (int a = 0; a < 16; ++a){ const int v = nhist[n0 + a]; nhmax = (v > nhmax) ? v : nhmax; }
    __syncthreads();

    for (int st = 1; st <= 78; ++st){
      const int thr  = (st <= 49) ? (50 - st) : -1;
      const int tsel = (st <= 49) ? st : 49;
      const bool skip = (nhmax <= thr);

      if (!skip){
        const short* hc = Hl + llo*264 + lhi*8;
        bf16x8 af[8];
        #pragma unroll
        for (int c = 0; c < 8; ++c) af[c] = *(const bf16x8*)(hc + c*32);

        f32x4 acc[4][2];
        #pragma unroll
        for (int g = 0; g < 4; ++g)
          #pragma unroll
          for (int t = 0; t < 2; ++t) acc[g][t] = (f32x4){0.f,0.f,0.f,0.f};

        #pragma unroll
        for (int c = 0; c < 4; ++c)
          #pragma unroll
          for (int g = 0; g < 4; ++g)
            #pragma unroll
            for (int t = 0; t < 2; ++t)
              acc[g][t] = __builtin_amdgcn_mfma_f32_16x16x32_bf16(af[c], wreg[c][g][t], acc[g][t], 0,0,0);
        #pragma unroll
        for (int c = 0; c < 4; ++c)
          #pragma unroll
          for (int g = 0; g < 4; ++g)
            #pragma unroll
            for (int t = 0; t < 2; ++t){
              const bf16x8 bw = *(const bf16x8*)(ldsW + (c*2048 + wv*512 + g*128 + t*64 + lane)*8);
              acc[g][t] = __builtin_amdgcn_mfma_f32_16x16x32_bf16(af[4+c], bw, acc[g][t], 0,0,0);
            }

        // gates for own half
        float2 rr[4];
        #pragma unroll
        for (int r = 0; r < 4; ++r)
          rr[r] = *(const float2*)(relS + (lhi*4 + r)*100 + 2*tsel);
        volatile float* wfv = wfL;
        short hpub[2][4];
        #pragma unroll
        for (int t = 0; t < 2; ++t){
          float wa[4], wb2[4], wbias[4];
          #pragma unroll
          for (int g = 0; g < 4; ++g){
            const int idx = ((wv*4 + g)*2 + t)*16 + llo;
            wa[g] = wfv[idx]; wb2[g] = wfv[512 + idx]; wbias[g] = wfv[1024 + idx];
          }
          const int e = h*128 + (wv<<5) + t*16 + llo;
          #pragma unroll
          for (int r = 0; r < 4; ++r){
            const float gi = acc[0][t][r] + rr[r].x*wa[0] + rr[r].y*wb2[0] + wbias[0];
            const float gf = acc[1][t][r] + rr[r].x*wa[1] + rr[r].y*wb2[1] + wbias[1];
            const float gg = acc[2][t][r] + rr[r].x*wa[2] + rr[r].y*wb2[2] + wbias[2];
            const float go = acc[3][t][r] + rr[r].x*wa[3] + rr[r].y*wb2[3] + wbias[3];
            const float c2 = sigf(gf)*C[r][t] + sigf(gi)*tanhfast(gg);
            const float h2 = sigf(go)*tanhfast(c2);
            const bool mk = nh4[r] > thr;
            if (mk) C[r][t] = c2;
            const short hold = Hl[(lhi*4 + r)*264 + e];
            short hnv; { __hip_bfloat16 hb = __float2bfloat16(h2); hnv = *(short*)&hb; }
            hpub[t][r] = mk ? hnv : hold;
          }
        }
        __syncthreads();   // all Hl reads of this step complete
        #pragma unroll
        for (int t = 0; t < 2; ++t){
          const int e = h*128 + (wv<<5) + t*16 + llo;
          #pragma unroll
          for (int r = 0; r < 4; ++r)
            Hl[(lhi*4 + r)*264 + e] = hpub[t][r];
        }
        __syncthreads();   // own half updated in LDS
        // publish own half to global (coalesced 16B)
        {
          const int a = tid >> 4, off = (tid & 15)*8;
          const int e = h*128 + off;
          *(uint4*)(HgS + (n0 + a)*256 + e) = *(const uint4*)(Hl + a*264 + e);
        }
        __syncthreads();   // drains vmcnt: stores in L2
        if (tid == 0){
          __hip_atomic_store(&flg[pb], st, __ATOMIC_RELEASE, __HIP_MEMORY_SCOPE_AGENT);
          while (__hip_atomic_load(&flg[pidx], __ATOMIC_ACQUIRE, __HIP_MEMORY_SCOPE_AGENT) < st) {}
        }
        __syncthreads();
        // pull partner half (L1 invalidated by tid0's acquire)
        {
          const int a = tid >> 4, off = (tid & 15)*8;
          const int e = (h^1)*128 + off;
          *(uint4*)(Hl + a*264 + e) = *(const uint4*)(HgS + (n0 + a)*256 + e);
        }
        __syncthreads();
      } else {
        if (tid == 0)
          __hip_atomic_store(&flg[pb], st, __ATOMIC_RELEASE, __HIP_MEMORY_SCOPE_AGENT);
      }

      if (st >= 49 && h == 0){
        const int s = st - 49;
        const int a = tid >> 4, sub = tid & 15;
        const short* hp = Hl + a*264 + sub*16;
        float z0 = 0.f, z1 = 0.f;
        #pragma unroll
        for (int i = 0; i < 16; ++i){
          const float hv = bfs(hp[i]);
          z0 += hv*vS[2*(sub*16 + i)];
          z1 += hv*vS[2*(sub*16 + i) + 1];
        }
        #pragma unroll
        for (int o = 8; o > 0; o >>= 1){
          z0 += __shfl_down(z0, o, 16);
          z1 += __shfl_down(z1, o, 16);
        }
        if (sub == 0){
          zS[s*32 + a*2]     = z0;
          zS[s*32 + a*2 + 1] = z1;
        }
      }
    }
    __syncthreads();
    if (h == 0){
      for (int i = tid; i < 960; i += 256){
        const int s = i >> 5, rem = i & 31;
        ws[WS_Z + (s*NAG + n0 + (rem >> 1))*2 + (rem & 1)] = zS[i];
      }
    }
  }
  else if (b == 0){
    // ---- target obs chain: 2 gate cols/thread, WhtT cached in VGPRs ----
    float* hT = (float*)smem;
    float* cT = hT + 128;
    float* gT = cT + 128;      // 512
    bf16x8 wc[2][16];          // 128 VGPR
    {
      const short* wp = (const short*)(ws + WS_WHT);
      #pragma unroll
      for (int q = 0; q < 2; ++q)
        #pragma unroll
        for (int f = 0; f < 16; ++f)
          wc[q][f] = *(const bf16x8*)(wp + (tid + q*256)*128 + f*8);
    }
    if (tid < 128){ hT[tid] = th0[tid]; cT[tid] = tc0[tid]; }
    __syncthreads();
    const int ths = thsp[0];
    int t0 = 51 - ths; if (t0 < 1) t0 = 1;
    for (int t = t0; t < 50; ++t){
      const float x0 = trel[2*t], x1 = trel[2*t+1];
      #pragma unroll
      for (int q = 0; q < 2; ++q){
        const int j = tid + q*256;
        float acc = x0*ws[WS_WFT + j] + x1*ws[WS_WFT + 512 + j] + ws[WS_BFT + j];
        #pragma unroll
        for (int f = 0; f < 16; ++f){
          #pragma unroll
          for (int i = 0; i < 8; ++i)
            acc += bfs(wc[q][f][i]) * hT[f*8 + i];
        }
        gT[j] = acc;
      }
      __syncthreads();
      if (tid < 128){
        const float ig = sigf(gT[tid]),          fg = sigf(gT[128 + tid]);
        const float gg = tanhfast(gT[256 + tid]), og = sigf(gT[384 + tid]);
        const float c2 = fg*cT[tid] + ig*gg;
        cT[tid] = c2; hT[tid] = og*tanhfast(c2);
      }
      __syncthreads();
    }
    if (tid < 128){ ws[WS_TH + tid] = hT[tid]; ws[WS_TC + tid] = cT[tid]; }
  }
  else {
    // ---- w49 precompute ----
    float* at  = (float*)smem;       // 64
    float* red = at + 64;            // 256
    float* uv  = red + 256;          // 3
    const int t = LH - 1;
    const float tr0 = trel[2*t], tr1 = trel[2*t+1];
    const float tp0 = tpos[2*t], tp1 = tpos[2*t+1];
    if (tid < ADIM) at[tid] = tr0*Wtatt[tid] + tr1*Wtatt[ADIM+tid] + btatt[tid];
    int cnt = 0;
    #pragma unroll
    for (int i = 0; i < 8; ++i) cnt += (nhist[tid + 256*i] > (LH - t)) ? 1 : 0;
    red[tid] = (float)cnt;
    __syncthreads();
    if (tid == 0){
      float u0=0.f,u1=0.f,v=0.f;
      for (int k=0;k<ADIM;k++){ u0 += Wnatt[k]*at[k]; u1 += Wnatt[ADIM+k]*at[k]; v += bnatt[k]*at[k]; }
      uv[0]=u0; uv[1]=u1; uv[2]=v;
    }
    for (int s = 128; s > 0; s >>= 1){ if (tid < s) red[tid] += red[tid+s]; __syncthreads(); }
    const float currN = red[0];
    __syncthreads();
    const float u0 = uv[0], u1 = uv[1], v = uv[2];
    const float scale = currN * 0.125f;
    float sc[8]; float smax = -3.0e38f;
    #pragma unroll
    for (int i = 0; i < 8; ++i){
      const int n = tid + 256*i;
      const float p0 = npos[n*100 + 2*t], p1 = npos[n*100 + 2*t + 1];
      float s = scale * ((tp0-p0)*u0 + (tp1-p1)*u1 + v);
      s = (nhist[n] > (LH - t)) ? s : -1.0e30f;
      sc[i] = s; smax = fmaxf(smax, s);
    }
    red[tid] = smax; __syncthreads();
    for (int s = 128; s > 0; s >>= 1){ if (tid<s) red[tid] = fmaxf(red[tid], red[tid+s]); __syncthreads(); }
    smax = red[0]; __syncthreads();
    float ssum = 0.f;
    #pragma unroll
    for (int i = 0; i < 8; ++i){ sc[i] = __expf(sc[i]-smax); ssum += sc[i]; }
    red[tid] = ssum; __syncthreads();
    for (int s = 128; s > 0; s >>= 1){ if (tid<s) red[tid] += red[tid+s]; __syncthreads(); }
    const float inv = 1.0f / red[0];
    #pragma unroll
    for (int i = 0; i < 8; ++i) ws[WS_W49 + tid + 256*i] = sc[i]*inv;
    if (tid == 0) ws[WS_CN] = currN;
  }
}

// ---- Phase B: all 30 pred steps in one block ---------------------------------
template<int K>
__device__ __forceinline__ void bredN(const float* v, volatile float* scratch,
                                      volatile float* outv, int tid){
  const int lane = tid & 63, wv = tid >> 6;
  #pragma unroll
  for (int k = 0; k < K; ++k){
    float x = v[k];
    #pragma unroll
    for (int o = 32; o > 0; o >>= 1) x += __shfl_down(x, o, 64);
    if (lane == 0) scratch[k*8 + wv] = x;
  }
  __syncthreads();
  if (tid == 0){
    #pragma unroll
    for (int k = 0; k < K; ++k){
      float s = 0.f;
      for (int i = 0; i < 8; ++i) s += scratch[k*8 + i];
      outv[k] = s;
    }
  }
  __syncthreads();
}

__device__ __forceinline__ float bredMax1(float x, volatile float* scratch,
                                          volatile float* outv, int tid){
  const int lane = tid & 63, wv = tid >> 6;
  #pragma unroll
  for (int o = 32; o > 0; o >>= 1) x = fmaxf(x, __shfl_down(x, o, 64));
  if (lane == 0) scratch[wv] = x;
  __syncthreads();
  if (tid == 0){
    float s = -3.0e38f;
    for (int i = 0; i < 8; ++i) s = fmaxf(s, scratch[i]);
    outv[0] = s;
  }
  __syncthreads();
  return outv[0];
}

__global__ __launch_bounds__(512, 1) void k_phaseB(
    const float* __restrict__ img, const float* __restrict__ tpos,
    const float* __restrict__ npos, const float* __restrict__ nh0,
    const float* __restrict__ Wpred, const float* __restrict__ bpred,
    const float* __restrict__ Wtatt, const float* __restrict__ btatt,
    const float* __restrict__ Wnatt, const float* __restrict__ bnatt,
    float* __restrict__ ws, float* __restrict__ out)
{
  __shared__ float p0s[NAG], p1s[NAG];
  __shared__ float th[128], tc[128], gl[512], at[64];
  __shared__ float scratch[24];
  __shared__ float bc[8];
  const int tid = threadIdx.x, lane = tid & 63, wv = tid >> 6;

  bf16x8 wreg[16];
  {
    const short* wp = (const short*)(ws + WS_WHT) + tid*128;
    #pragma unroll
    for (int f = 0; f < 16; ++f) wreg[f] = *(const bf16x8*)(wp + f*8);
  }
  for (int n = tid; n < NAG; n += 512){
    p0s[n] = npos[n*100 + 98];
    p1s[n] = npos[n*100 + 99];
  }
  if (tid < 128){ th[tid] = ws[WS_TH + tid]; tc[tid] = ws[WS_TC + tid]; }

  {
    float v[2] = {0.f, 0.f};
    for (int k = tid; k < CNND; k += 512){
      v[0] += img[k]*Wpred[2*(128 + k)];
      v[1] += img[k]*Wpred[2*(128 + k) + 1];
    }
    bredN<2>(v, scratch, bc, tid);
  }
  const float imgW0 = bc[0], imgW1 = bc[1];
  {
    float v[2] = {0.f, 0.f};
    if (tid < 256){
      v[0] = nh0[tid]*Wpred[2*(128 + CNND + tid)];
      v[1] = nh0[tid]*Wpred[2*(128 + CNND + tid) + 1];
    }
    bredN<2>(v, scratch, bc + 2, tid);
  }
  const float fb0 = bc[2], fb1 = bc[3];
  const float currN = ws[WS_CN];
  float pos0 = tpos[98], pos1 = tpos[99];
  float u0 = 0.f, u1 = 0.f, A = 0.f;
  __syncthreads();

  for (int s = 0; s < PP; ++s){
    const float* zs = ws + WS_Z + s*(NAG*2);
    float hv0, hv1;
    if (s == 0){
      if (currN >= 1.0f){
        float v[2] = {0.f, 0.f};
        for (int n = tid; n < NAG; n += 512){
          const float w = ws[WS_W49 + n];
          v[0] += w*zs[2*n]; v[1] += w*zs[2*n + 1];
        }
        bredN<2>(v, scratch, bc, tid);
        hv0 = bc[0]; hv1 = bc[1];
      } else { hv0 = fb0; hv1 = fb1; }
    } else {
      float sc[4], mx = -3.0e38f;
      #pragma unroll
      for (int i = 0; i < 4; ++i){
        const int n = tid + 512*i;
        sc[i] = 256.0f * (A - (p0s[n]*u0 + p1s[n]*u1));
        mx = fmaxf(mx, sc[i]);
      }
      mx = bredMax1(mx, scratch, bc + 7, tid);
      float v[3] = {0.f, 0.f, 0.f};
      #pragma unroll
      for (int i = 0; i < 4; ++i){
        const int n = tid + 512*i;
        const float e = __expf(sc[i] - mx);
        v[0] += e; v[1] += e*zs[2*n]; v[2] += e*zs[2*n + 1];
      }
      bredN<3>(v, scratch, bc, tid);
      const float inv = 1.0f / bc[0];
      hv0 = bc[1]*inv; hv1 = bc[2]*inv;
    }
    {
      float v[2] = {0.f, 0.f};
      if (tid < 128){
        v[0] = th[tid]*Wpred[2*tid];
        v[1] = th[tid]*Wpred[2*tid + 1];
      }
      bredN<2>(v, scratch, bc + 2, tid);
    }
    const float pr0 = bc[2] + imgW0 + hv0 + bpred[0];
    const float pr1 = bc[3] + imgW1 + hv1 + bpred[1];
    if (tid == 0){ out[2*s] = pr0; out[2*s + 1] = pr1; }
    pos0 += pr0; pos1 += pr1;

    {
      float g = pr0*ws[WS_WFT + tid] + pr1*ws[WS_WFT + 512 + tid] + ws[WS_BFT + tid];
      #pragma unroll
      for (int f = 0; f < 16; ++f){
        #pragma unroll
        for (int i = 0; i < 8; ++i)
          g += bfs(wreg[f][i]) * th[f*8 + i];
      }
      gl[tid] = g;
    }
    __syncthreads();
    float hnew = 0.f, cnew = 0.f;
    if (tid < 128){
      const float ig = sigf(gl[tid]),           fg = sigf(gl[128 + tid]);
      const float gg = tanhfast(gl[256 + tid]), og = sigf(gl[384 + tid]);
      cnew = fg*tc[tid] + ig*gg;
      hnew = og*tanhfast(cnew);
    }
    __syncthreads();
    if (tid < 128){ th[tid] = hnew; tc[tid] = cnew; }

    if (tid < ADIM) at[tid] = pr0*Wtatt[tid] + pr1*Wtatt[ADIM + tid] + btatt[tid];
    __syncthreads();
    if (wv == 0){
      float uu0 = Wnatt[lane]*at[lane];
      float uu1 = Wnatt[ADIM + lane]*at[lane];
      float vv  = bnatt[lane]*at[lane];
      #pragma unroll
      for (int o = 32; o > 0; o >>= 1){
        uu0 += __shfl_down(uu0, o, 64);
        uu1 += __shfl_down(uu1, o, 64);
        vv  += __shfl_down(vv,  o, 64);
      }
      if (lane == 0){
        bc[4] = uu0; bc[5] = uu1;
        bc[6] = pos0*uu0 + pos1*uu1 + vv;
      }
    }
    __syncthreads();
    u0 = bc[4]; u1 = bc[5]; A = bc[6];
  }
}

extern "C" void kernel_launch(void* const* d_in, const int* in_sizes, int n_in,
                              void* d_out, int out_size, void* d_ws, size_t ws_size,
                              hipStream_t stream) {
  const float* img   = (const float*)d_in[0];
  const float* tpos  = (const float*)d_in[1];
  const float* trel  = (const float*)d_in[2];
  const float* npos  = (const float*)d_in[3];
  const float* nrel  = (const float*)d_in[4];
  const int*   nhist = (const int*)d_in[5];
  const int*   ths   = (const int*)d_in[6];
  const float* th0   = (const float*)d_in[7];
  const float* tc0   = (const float*)d_in[8];
  const float* Wtemb = (const float*)d_in[9];
  const float* btemb = (const float*)d_in[10];
  const float* Wiht  = (const float*)d_in[11];
  const float* Whht  = (const float*)d_in[12];
  const float* biht  = (const float*)d_in[13];
  const float* bhht  = (const float*)d_in[14];
  const float* Wtatt = (const float*)d_in[15];
  const float* btatt = (const float*)d_in[16];
  const float* nh0   = (const float*)d_in[17];
  const float* nc0   = (const float*)d_in[18];
  const float* Wnemb = (const float*)d_in[19];
  const float* bnemb = (const float*)d_in[20];
  const float* Wihn  = (const float*)d_in[21];
  const float* Whhn  = (const float*)d_in[22];
  const float* bihn  = (const float*)d_in[23];
  const float* bhhn  = (const float*)d_in[24];
  const float* Wnatt = (const float*)d_in[25];
  const float* bnatt = (const float*)d_in[26];
  const float* Wpred = (const float*)d_in[27];
  const float* bpred = (const float*)d_in[28];
  float* ws  = (float*)d_ws;
  float* out = (float*)d_out;

  const int ldsA = 157952;

  k_prep<<<257, 256, 0, stream>>>(Whhn, Whht, Wnemb, bnemb, Wihn, bihn, bhhn,
                                  Wtemb, btemb, Wiht, biht, bhht, ws);
  k_phaseA<<<258, 256, ldsA, stream>>>(nh0, nc0, nrel, nhist, Wpred,
                                       trel, ths, Whht, th0, tc0,
                                       tpos, npos, Wtatt, btatt, Wnatt, bnatt, ws);
  k_phaseB<<<1, 512, 0, stream>>>(img, tpos, npos, nh0, Wpred, bpred,
                                  Wtatt, btatt, Wnatt, bnatt, ws, out);
}

// Round 13
// 840.895 us; speedup vs baseline: 1.3952x; 1.3952x over previous
//
#include <hip/hip_runtime.h>
#include <hip/hip_bf16.h>
#include <cstdint>

#define LH   50
#define PP   30
#define NAG  2048
#define NHID 128
#define EHID 256
#define ADIM 64
#define CNND 2048

typedef __attribute__((ext_vector_type(8))) short bf16x8;
typedef __attribute__((ext_vector_type(4))) float f32x4;

// ---- workspace layout (float slots) -----------------------------------------
// W image: [c=8][s=4][j=1024][i=8] bf16  (k = c*32 + s*8 + i)
enum : int {
  WS_WT  = 0,        // 131072 fl (512KB)
  WS_WHT = 131072,   // bf16 WhtT[512][128] -> 32768
  WS_WFN = 163840,   // wf0[1024] wf1[1024]
  WS_BFN = 165888,   // wb[1024]
  WS_WFT = 166912,   // 2*512
  WS_BFT = 167936,   // 512
  WS_TH  = 168448,   // 128
  WS_TC  = 168576,   // 128
  WS_W49 = 168704,   // 2048
  WS_CN  = 170752,   // 1 (+3 pad)
  WS_Z   = 170756,   // 30*2048*2
  WS_FLG = 293636,   // 256 ints (pair sync flags)
  WS_HG  = 293892,   // bf16 H exchange [2 parity][2048][256] -> 262144 fl
  WS_END = 556036
};

__device__ __forceinline__ float sigf(float x){ return 1.0f/(1.0f + __expf(-x)); }
__device__ __forceinline__ float tanhfast(float x){
  x = fminf(15.0f, fmaxf(-15.0f, x));
  float e = __expf(2.0f*x);
  return (e - 1.0f)/(e + 1.0f);
}
__device__ __forceinline__ float bfs(short s){
  return __uint_as_float(((unsigned)(unsigned short)s) << 16);
}
__device__ __forceinline__ void ast(unsigned* p, unsigned v){
  __hip_atomic_store(p, v, __ATOMIC_RELAXED, __HIP_MEMORY_SCOPE_AGENT);
}
__device__ __forceinline__ unsigned ald(const unsigned* p){
  return __hip_atomic_load(p, __ATOMIC_RELAXED, __HIP_MEMORY_SCOPE_AGENT);
}

// ---- prep grid (259 blocks x 256):
//   b<256  : W transpose -> [c][s][j][8] image
//   b==256 : folds + WhtT + flag zero (atomic)
//   b==257 : target obs chain (self-computed folds, f32 Whht stream)
//   b==258 : w49 precompute
__global__ void k_prep(const float* __restrict__ Whhn, const float* __restrict__ Whht,
                       const float* __restrict__ Wnemb, const float* __restrict__ bnemb,
                       const float* __restrict__ Wihn,  const float* __restrict__ bihn,
                       const float* __restrict__ bhhn,
                       const float* __restrict__ Wtemb, const float* __restrict__ btemb,
                       const float* __restrict__ Wiht,  const float* __restrict__ biht,
                       const float* __restrict__ bhht,
                       const float* __restrict__ trel,  const int* __restrict__ thsp,
                       const float* __restrict__ th0,   const float* __restrict__ tc0,
                       const float* __restrict__ tpos,  const float* __restrict__ npos,
                       const int* __restrict__ nhist,
                       const float* __restrict__ Wtatt, const float* __restrict__ btatt,
                       const float* __restrict__ Wnatt, const float* __restrict__ bnatt,
                       float* __restrict__ ws)
{
  __shared__ float ps[2304];
  const int b = blockIdx.x, tid = threadIdx.x;
  if (b < 256){
    float (*t)[33] = (float(*)[33])ps;
    __hip_bfloat16* WT = (__hip_bfloat16*)(ws + WS_WT);
    const int tx = tid & 31, ty = tid >> 5;     // ty in [0,8)
    const int j0 = (b & 31) << 5;
    const int c  = b >> 5;                      // k-chunk 0..7
    const int e0 = c << 5;
    #pragma unroll
    for (int r = 0; r < 4; ++r)
      t[ty + 8*r][tx] = Whhn[(e0 + ty + 8*r)*1024 + j0 + tx];
    __syncthreads();
    #pragma unroll
    for (int r = 0; r < 4; ++r)
      WT[c*32768 + r*8192 + (j0 + tx)*8 + ty] = __float2bfloat16(t[ty + 8*r][tx]);
  } else if (b == 256){
    for (int j = tid; j < 1024; j += 256){
      float a0=0.f, a1=0.f, ab=0.f;
      for (int k=0;k<64;k++){
        const float w = Wihn[k*1024 + j];
        a0 += Wnemb[k]*w; a1 += Wnemb[64+k]*w; ab += bnemb[k]*w;
      }
      ws[WS_WFN + j]        = a0;
      ws[WS_WFN + 1024 + j] = a1;
      ws[WS_BFN + j]        = ab + bihn[j] + bhhn[j];
    }
    for (int j = tid; j < 512; j += 256){
      float a0=0.f, a1=0.f, ab=0.f;
      for (int k=0;k<64;k++){
        const float w = Wiht[k*512 + j];
        a0 += Wtemb[k]*w; a1 += Wtemb[64+k]*w; ab += btemb[k]*w;
      }
      ws[WS_WFT + j]       = a0;
      ws[WS_WFT + 512 + j] = a1;
      ws[WS_BFT + j]       = ab + biht[j] + bhht[j];
    }
    __hip_bfloat16* WTt = (__hip_bfloat16*)(ws + WS_WHT);
    for (int j = tid; j < 512; j += 256)
      for (int k = 0; k < 128; ++k)
        WTt[j*128 + k] = __float2bfloat16(Whht[k*512 + j]);
    // zero pair flags with agent-scope atomics (replay-safe, MALL-visible)
    ast((unsigned*)(ws + WS_FLG) + tid, 0u);
  } else if (b == 257){
    // ---- target obs chain; folds computed locally ----
    float* hT  = ps;          // 128
    float* cT  = ps + 128;    // 128
    float* gT  = ps + 256;    // 512
    float* wfa = ps + 768;    // 512
    float* wfb = ps + 1280;   // 512
    float* bfT = ps + 1792;   // 512
    #pragma unroll
    for (int q = 0; q < 2; ++q){
      const int j = tid + q*256;
      float a0=0.f, a1=0.f, ab=0.f;
      for (int k=0;k<64;k++){
        const float w = Wiht[k*512 + j];
        a0 += Wtemb[k]*w; a1 += Wtemb[64+k]*w; ab += btemb[k]*w;
      }
      wfa[j] = a0; wfb[j] = a1; bfT[j] = ab + biht[j] + bhht[j];
    }
    if (tid < 128){ hT[tid] = th0[tid]; cT[tid] = tc0[tid]; }
    __syncthreads();
    const int ths = thsp[0];
    int t0 = 51 - ths; if (t0 < 1) t0 = 1;
    for (int t = t0; t < 50; ++t){
      const float x0 = trel[2*t], x1 = trel[2*t+1];
      #pragma unroll
      for (int q = 0; q < 2; ++q){
        const int j = tid + q*256;
        float acc = x0*wfa[j] + x1*wfb[j] + bfT[j];
        for (int k = 0; k < 128; ++k) acc += hT[k]*Whht[k*512 + j];
        gT[j] = acc;
      }
      __syncthreads();
      if (tid < 128){
        const float ig = sigf(gT[tid]),          fg = sigf(gT[128 + tid]);
        const float gg = tanhfast(gT[256 + tid]), og = sigf(gT[384 + tid]);
        const float c2 = fg*cT[tid] + ig*gg;
        cT[tid] = c2; hT[tid] = og*tanhfast(c2);
      }
      __syncthreads();
    }
    if (tid < 128){ ws[WS_TH + tid] = hT[tid]; ws[WS_TC + tid] = cT[tid]; }
  } else {
    // ---- w49 precompute ----
    float* at  = ps;          // 64
    float* red = ps + 64;     // 256
    float* uv  = ps + 320;    // 3
    const int t = LH - 1;
    const float tr0 = trel[2*t], tr1 = trel[2*t+1];
    const float tp0 = tpos[2*t], tp1 = tpos[2*t+1];
    if (tid < ADIM) at[tid] = tr0*Wtatt[tid] + tr1*Wtatt[ADIM+tid] + btatt[tid];
    int cnt = 0;
    #pragma unroll
    for (int i = 0; i < 8; ++i) cnt += (nhist[tid + 256*i] > (LH - t)) ? 1 : 0;
    red[tid] = (float)cnt;
    __syncthreads();
    if (tid == 0){
      float u0=0.f,u1=0.f,v=0.f;
      for (int k=0;k<ADIM;k++){ u0 += Wnatt[k]*at[k]; u1 += Wnatt[ADIM+k]*at[k]; v += bnatt[k]*at[k]; }
      uv[0]=u0; uv[1]=u1; uv[2]=v;
    }
    for (int s = 128; s > 0; s >>= 1){ if (tid < s) red[tid] += red[tid+s]; __syncthreads(); }
    const float currN = red[0];
    __syncthreads();
    const float u0 = uv[0], u1 = uv[1], v = uv[2];
    const float scale = currN * 0.125f;
    float sc[8]; float smax = -3.0e38f;
    #pragma unroll
    for (int i = 0; i < 8; ++i){
      const int n = tid + 256*i;
      const float p0 = npos[n*100 + 2*t], p1 = npos[n*100 + 2*t + 1];
      float s = scale * ((tp0-p0)*u0 + (tp1-p1)*u1 + v);
      s = (nhist[n] > (LH - t)) ? s : -1.0e30f;
      sc[i] = s; smax = fmaxf(smax, s);
    }
    red[tid] = smax; __syncthreads();
    for (int s = 128; s > 0; s >>= 1){ if (tid<s) red[tid] = fmaxf(red[tid], red[tid+s]); __syncthreads(); }
    smax = red[0]; __syncthreads();
    float ssum = 0.f;
    #pragma unroll
    for (int i = 0; i < 8; ++i){ sc[i] = __expf(sc[i]-smax); ssum += sc[i]; }
    red[tid] = ssum; __syncthreads();
    for (int s = 128; s > 0; s >>= 1){ if (tid<s) red[tid] += red[tid+s]; __syncthreads(); }
    const float inv = 1.0f / red[0];
    #pragma unroll
    for (int i = 0; i < 8; ++i) ws[WS_W49 + tid + 256*i] = sc[i]*inv;
    if (tid == 0) ws[WS_CN] = currN;
  }
}

// ---- Phase A: 256 pair blocks exactly (grid == CU count) ----------------------
// pb = blockIdx.x: agrp = pb&127 (16 agents), h = pb>>7 (e-half), partner pb^128.
// W slice (512 j x 256 k = 256KB) fully resident: k-chunks 0..3 in VGPR,
// 4..7 in LDS. Per step: MFMA -> gates -> parity-buffered H-half exchange via
// relaxed agent atomics (per-dword MALL access, NO cache-wide fences).
// dyn LDS: ldsW 131072 | Hl 8448 | relS 6400 | vS 2048 | zS 3840 | wfL 6144
__global__ __launch_bounds__(256, 1) void k_phaseA(
    const float* __restrict__ nh0, const float* __restrict__ nc0,
    const float* __restrict__ nrel, const int* __restrict__ nhist,
    const float* __restrict__ Wpred,
    float* __restrict__ ws)
{
  extern __shared__ char smem[];
  const int tid = threadIdx.x;
  const int wv = tid >> 6, lane = tid & 63;
  const int lhi = lane >> 4, llo = lane & 15;

  const int pb = blockIdx.x;
  const int agrp = pb & 127;
  const int h    = pb >> 7;
  const int pidx = pb ^ 128;
  const int n0   = agrp << 4;
  unsigned* flg = (unsigned*)(ws + WS_FLG);
  short* HgS = (short*)(ws + WS_HG);

  short* ldsW = (short*)smem;                    // 131072 B
  short* Hl   = (short*)(smem + 131072);         // [16][264] shorts
  float* relS = (float*)(smem + 139520);         // 1600 fl
  float* vS   = (float*)(smem + 145920);         // 512 fl
  float* zS   = (float*)(smem + 147968);         // 960 fl
  float* wfL  = (float*)(smem + 151808);         // 1536 fl
  const short* wt = (const short*)(ws + WS_WT);

  // ---- one-time: VGPR W (k-chunks 0..3) ----
  bf16x8 wreg[4][4][2];    // [c][g][t] -> 128 VGPR
  #pragma unroll
  for (int c = 0; c < 4; ++c)
    #pragma unroll
    for (int g = 0; g < 4; ++g)
      #pragma unroll
      for (int t = 0; t < 2; ++t){
        const int j = g*256 + h*128 + (wv<<5) + t*16 + llo;
        wreg[c][g][t] = *(const bf16x8*)(wt + c*32768 + lhi*8192 + j*8);
      }
  // ---- one-time: LDS W (k-chunks 4..7) ----
  // layout: u = c*2048 + wv*512 + g*128 + t*64 + lane  (8 shorts per u)
  for (int u = tid; u < 8192; u += 256){
    const int lane_u = u & 63;
    const int t_u  = (u >> 6) & 1;
    const int g_u  = (u >> 7) & 3;
    const int wv_u = (u >> 9) & 3;
    const int c_u  = (u >> 11) & 3;
    const int llo_u = lane_u & 15, lhi_u = lane_u >> 4;
    const int j_u = g_u*256 + h*128 + wv_u*32 + t_u*16 + llo_u;
    *(uint4*)(ldsW + u*8) = *(const uint4*)(wt + (4+c_u)*32768 + lhi_u*8192 + j_u*8);
  }
  // folded gate consts for own j-set
  for (int i = tid; i < 512; i += 256){
    const int llo_i = i & 15, t_i = (i >> 4) & 1, g_i = (i >> 5) & 3, wv_i = (i >> 7) & 3;
    const int j = g_i*256 + h*128 + wv_i*32 + t_i*16 + llo_i;
    wfL[i]        = ws[WS_WFN + j];
    wfL[512 + i]  = ws[WS_WFN + 1024 + j];
    wfL[1024 + i] = ws[WS_BFN + j];
  }
  for (int i = tid; i < 1600; i += 256){
    const int a = i / 100, r = i % 100;
    relS[a*100 + r] = nrel[(n0 + a)*100 + r];
  }
  vS[2*tid]   = Wpred[2*(NHID + CNND + tid)];
  vS[2*tid+1] = Wpred[2*(NHID + CNND + tid) + 1];
  for (int i = tid; i < 4096; i += 256){
    const int a = i >> 8, e = i & 255;
    ((__hip_bfloat16*)Hl)[a*264 + e] = __float2bfloat16(nh0[e]);
  }
  float C[4][2];
  #pragma unroll
  for (int r = 0; r < 4; ++r)
    #pragma unroll
    for (int t = 0; t < 2; ++t)
      C[r][t] = nc0[h*128 + (wv<<5) + t*16 + llo];
  int nh4[4];
  #pragma unroll
  for (int r = 0; r < 4; ++r) nh4[r] = nhist[n0 + lhi*4 + r];
  int nhmax = 0;
  for (int a = 0; a < 16; ++a){ const int v = nhist[n0 + a]; nhmax = (v > nhmax) ? v : nhmax; }
  __syncthreads();

  for (int st = 1; st <= 78; ++st){
    const int thr  = (st <= 49) ? (50 - st) : -1;
    const int tsel = (st <= 49) ? st : 49;
    const bool skip = (nhmax <= thr);

    if (!skip){
      const short* hc = Hl + llo*264 + lhi*8;
      bf16x8 af[8];
      #pragma unroll
      for (int c = 0; c < 8; ++c) af[c] = *(const bf16x8*)(hc + c*32);

      f32x4 acc[4][2];
      #pragma unroll
      for (int g = 0; g < 4; ++g)
        #pragma unroll
        for (int t = 0; t < 2; ++t) acc[g][t] = (f32x4){0.f,0.f,0.f,0.f};

      #pragma unroll
      for (int c = 0; c < 4; ++c)
        #pragma unroll
        for (int g = 0; g < 4; ++g)
          #pragma unroll
          for (int t = 0; t < 2; ++t)
            acc[g][t] = __builtin_amdgcn_mfma_f32_16x16x32_bf16(af[c], wreg[c][g][t], acc[g][t], 0,0,0);
      #pragma unroll
      for (int c = 0; c < 4; ++c)
        #pragma unroll
        for (int g = 0; g < 4; ++g)
          #pragma unroll
          for (int t = 0; t < 2; ++t){
            const bf16x8 bw = *(const bf16x8*)(ldsW + (c*2048 + wv*512 + g*128 + t*64 + lane)*8);
            acc[g][t] = __builtin_amdgcn_mfma_f32_16x16x32_bf16(af[4+c], bw, acc[g][t], 0,0,0);
          }

      // gates for own half
      float2 rr[4];
      #pragma unroll
      for (int r = 0; r < 4; ++r)
        rr[r] = *(const float2*)(relS + (lhi*4 + r)*100 + 2*tsel);
      volatile float* wfv = wfL;
      short hpub[2][4];
      #pragma unroll
      for (int t = 0; t < 2; ++t){
        float wa[4], wb2[4], wbias[4];
        #pragma unroll
        for (int g = 0; g < 4; ++g){
          const int idx = ((wv*4 + g)*2 + t)*16 + llo;
          wa[g] = wfv[idx]; wb2[g] = wfv[512 + idx]; wbias[g] = wfv[1024 + idx];
        }
        const int e = h*128 + (wv<<5) + t*16 + llo;
        #pragma unroll
        for (int r = 0; r < 4; ++r){
          const float gi = acc[0][t][r] + rr[r].x*wa[0] + rr[r].y*wb2[0] + wbias[0];
          const float gf = acc[1][t][r] + rr[r].x*wa[1] + rr[r].y*wb2[1] + wbias[1];
          const float gg = acc[2][t][r] + rr[r].x*wa[2] + rr[r].y*wb2[2] + wbias[2];
          const float go = acc[3][t][r] + rr[r].x*wa[3] + rr[r].y*wb2[3] + wbias[3];
          const float c2 = sigf(gf)*C[r][t] + sigf(gi)*tanhfast(gg);
          const float h2 = sigf(go)*tanhfast(c2);
          const bool mk = nh4[r] > thr;
          if (mk) C[r][t] = c2;
          const short hold = Hl[(lhi*4 + r)*264 + e];
          short hnv; { __hip_bfloat16 hb = __float2bfloat16(h2); hnv = *(short*)&hb; }
          hpub[t][r] = mk ? hnv : hold;
        }
      }
      __syncthreads();   // all Hl reads of this step complete
      #pragma unroll
      for (int t = 0; t < 2; ++t){
        const int e = h*128 + (wv<<5) + t*16 + llo;
        #pragma unroll
        for (int r = 0; r < 4; ++r)
          Hl[(lhi*4 + r)*264 + e] = hpub[t][r];
      }
      __syncthreads();   // own half updated in LDS
      // publish own half -> Hg[parity] via relaxed agent atomics (MALL)
      {
        const int a = tid >> 4, i = tid & 15;
        const uint4 v = *(const uint4*)(Hl + a*264 + h*128 + i*8);
        unsigned* dst = (unsigned*)(HgS + (st & 1)*524288 + (n0 + a)*256 + h*128) + i*4;
        ast(dst+0, v.x); ast(dst+1, v.y); ast(dst+2, v.z); ast(dst+3, v.w);
      }
      __syncthreads();   // drains vmcnt(0): all stores at coherent point
      if (tid == 0){
        ast(&flg[pb], (unsigned)st);
        while ((int)ald(&flg[pidx]) < st) {}
      }
      __syncthreads();
      // pull partner half
      {
        const int a = tid >> 4, i = tid & 15;
        const unsigned* src = (const unsigned*)(HgS + (st & 1)*524288 + (n0 + a)*256 + (h^1)*128) + i*4;
        uint4 v;
        v.x = ald(src+0); v.y = ald(src+1); v.z = ald(src+2); v.w = ald(src+3);
        *(uint4*)(Hl + a*264 + (h^1)*128 + i*8) = v;
      }
      __syncthreads();
    } else {
      if (tid == 0) ast(&flg[pb], (unsigned)st);
    }

    if (st >= 49 && h == 0){
      const int s = st - 49;
      const int a = tid >> 4, sub = tid & 15;
      const short* hp = Hl + a*264 + sub*16;
      float z0 = 0.f, z1 = 0.f;
      #pragma unroll
      for (int i = 0; i < 16; ++i){
        const float hv = bfs(hp[i]);
        z0 += hv*vS[2*(sub*16 + i)];
        z1 += hv*vS[2*(sub*16 + i) + 1];
      }
      #pragma unroll
      for (int o = 8; o > 0; o >>= 1){
        z0 += __shfl_down(z0, o, 16);
        z1 += __shfl_down(z1, o, 16);
      }
      if (sub == 0){
        zS[s*32 + a*2]     = z0;
        zS[s*32 + a*2 + 1] = z1;
      }
    }
  }
  __syncthreads();
  if (h == 0){
    for (int i = tid; i < 960; i += 256){
      const int s = i >> 5, rem = i & 31;
      ws[WS_Z + (s*NAG + n0 + (rem >> 1))*2 + (rem & 1)] = zS[i];
    }
  }
}

// ---- Phase B: all 30 pred steps in one block ---------------------------------
template<int K>
__device__ __forceinline__ void bredN(const float* v, volatile float* scratch,
                                      volatile float* outv, int tid){
  const int lane = tid & 63, wv = tid >> 6;
  #pragma unroll
  for (int k = 0; k < K; ++k){
    float x = v[k];
    #pragma unroll
    for (int o = 32; o > 0; o >>= 1) x += __shfl_down(x, o, 64);
    if (lane == 0) scratch[k*8 + wv] = x;
  }
  __syncthreads();
  if (tid == 0){
    #pragma unroll
    for (int k = 0; k < K; ++k){
      float s = 0.f;
      for (int i = 0; i < 8; ++i) s += scratch[k*8 + i];
      outv[k] = s;
    }
  }
  __syncthreads();
}

__device__ __forceinline__ float bredMax1(float x, volatile float* scratch,
                                          volatile float* outv, int tid){
  const int lane = tid & 63, wv = tid >> 6;
  #pragma unroll
  for (int o = 32; o > 0; o >>= 1) x = fmaxf(x, __shfl_down(x, o, 64));
  if (lane == 0) scratch[wv] = x;
  __syncthreads();
  if (tid == 0){
    float s = -3.0e38f;
    for (int i = 0; i < 8; ++i) s = fmaxf(s, scratch[i]);
    outv[0] = s;
  }
  __syncthreads();
  return outv[0];
}

__global__ __launch_bounds__(512, 1) void k_phaseB(
    const float* __restrict__ img, const float* __restrict__ tpos,
    const float* __restrict__ npos, const float* __restrict__ nh0,
    const float* __restrict__ Wpred, const float* __restrict__ bpred,
    const float* __restrict__ Wtatt, const float* __restrict__ btatt,
    const float* __restrict__ Wnatt, const float* __restrict__ bnatt,
    float* __restrict__ ws, float* __restrict__ out)
{
  __shared__ float p0s[NAG], p1s[NAG];
  __shared__ float th[128], tc[128], gl[512], at[64];
  __shared__ float scratch[24];
  __shared__ float bc[8];
  const int tid = threadIdx.x, lane = tid & 63, wv = tid >> 6;

  bf16x8 wreg[16];
  {
    const short* wp = (const short*)(ws + WS_WHT) + tid*128;
    #pragma unroll
    for (int f = 0; f < 16; ++f) wreg[f] = *(const bf16x8*)(wp + f*8);
  }
  for (int n = tid; n < NAG; n += 512){
    p0s[n] = npos[n*100 + 98];
    p1s[n] = npos[n*100 + 99];
  }
  if (tid < 128){ th[tid] = ws[WS_TH + tid]; tc[tid] = ws[WS_TC + tid]; }

  {
    float v[2] = {0.f, 0.f};
    for (int k = tid; k < CNND; k += 512){
      v[0] += img[k]*Wpred[2*(128 + k)];
      v[1] += img[k]*Wpred[2*(128 + k) + 1];
    }
    bredN<2>(v, scratch, bc, tid);
  }
  const float imgW0 = bc[0], imgW1 = bc[1];
  {
    float v[2] = {0.f, 0.f};
    if (tid < 256){
      v[0] = nh0[tid]*Wpred[2*(128 + CNND + tid)];
      v[1] = nh0[tid]*Wpred[2*(128 + CNND + tid) + 1];
    }
    bredN<2>(v, scratch, bc + 2, tid);
  }
  const float fb0 = bc[2], fb1 = bc[3];
  const float currN = ws[WS_CN];
  float pos0 = tpos[98], pos1 = tpos[99];
  float u0 = 0.f, u1 = 0.f, A = 0.f;
  __syncthreads();

  for (int s = 0; s < PP; ++s){
    const float* zs = ws + WS_Z + s*(NAG*2);
    float hv0, hv1;
    if (s == 0){
      if (currN >= 1.0f){
        float v[2] = {0.f, 0.f};
        for (int n = tid; n < NAG; n += 512){
          const float w = ws[WS_W49 + n];
          v[0] += w*zs[2*n]; v[1] += w*zs[2*n + 1];
        }
        bredN<2>(v, scratch, bc, tid);
        hv0 = bc[0]; hv1 = bc[1];
      } else { hv0 = fb0; hv1 = fb1; }
    } else {
      float sc[4], mx = -3.0e38f;
      #pragma unroll
      for (int i = 0; i < 4; ++i){
        const int n = tid + 512*i;
        sc[i] = 256.0f * (A - (p0s[n]*u0 + p1s[n]*u1));
        mx = fmaxf(mx, sc[i]);
      }
      mx = bredMax1(mx, scratch, bc + 7, tid);
      float v[3] = {0.f, 0.f, 0.f};
      #pragma unroll
      for (int i = 0; i < 4; ++i){
        const int n = tid + 512*i;
        const float e = __expf(sc[i] - mx);
        v[0] += e; v[1] += e*zs[2*n]; v[2] += e*zs[2*n + 1];
      }
      bredN<3>(v, scratch, bc, tid);
      const float inv = 1.0f / bc[0];
      hv0 = bc[1]*inv; hv1 = bc[2]*inv;
    }
    {
      float v[2] = {0.f, 0.f};
      if (tid < 128){
        v[0] = th[tid]*Wpred[2*tid];
        v[1] = th[tid]*Wpred[2*tid + 1];
      }
      bredN<2>(v, scratch, bc + 2, tid);
    }
    const float pr0 = bc[2] + imgW0 + hv0 + bpred[0];
    const float pr1 = bc[3] + imgW1 + hv1 + bpred[1];
    if (tid == 0){ out[2*s] = pr0; out[2*s + 1] = pr1; }
    pos0 += pr0; pos1 += pr1;

    {
      float g = pr0*ws[WS_WFT + tid] + pr1*ws[WS_WFT + 512 + tid] + ws[WS_BFT + tid];
      #pragma unroll
      for (int f = 0; f < 16; ++f){
        #pragma unroll
        for (int i = 0; i < 8; ++i)
          g += bfs(wreg[f][i]) * th[f*8 + i];
      }
      gl[tid] = g;
    }
    __syncthreads();
    float hnew = 0.f, cnew = 0.f;
    if (tid < 128){
      const float ig = sigf(gl[tid]),           fg = sigf(gl[128 + tid]);
      const float gg = tanhfast(gl[256 + tid]), og = sigf(gl[384 + tid]);
      cnew = fg*tc[tid] + ig*gg;
      hnew = og*tanhfast(cnew);
    }
    __syncthreads();
    if (tid < 128){ th[tid] = hnew; tc[tid] = cnew; }

    if (tid < ADIM) at[tid] = pr0*Wtatt[tid] + pr1*Wtatt[ADIM + tid] + btatt[tid];
    __syncthreads();
    if (wv == 0){
      float uu0 = Wnatt[lane]*at[lane];
      float uu1 = Wnatt[ADIM + lane]*at[lane];
      float vv  = bnatt[lane]*at[lane];
      #pragma unroll
      for (int o = 32; o > 0; o >>= 1){
        uu0 += __shfl_down(uu0, o, 64);
        uu1 += __shfl_down(uu1, o, 64);
        vv  += __shfl_down(vv,  o, 64);
      }
      if (lane == 0){
        bc[4] = uu0; bc[5] = uu1;
        bc[6] = pos0*uu0 + pos1*uu1 + vv;
      }
    }
    __syncthreads();
    u0 = bc[4]; u1 = bc[5]; A = bc[6];
  }
}

extern "C" void kernel_launch(void* const* d_in, const int* in_sizes, int n_in,
                              void* d_out, int out_size, void* d_ws, size_t ws_size,
                              hipStream_t stream) {
  const float* img   = (const float*)d_in[0];
  const float* tpos  = (const float*)d_in[1];
  const float* trel  = (const float*)d_in[2];
  const float* npos  = (const float*)d_in[3];
  const float* nrel  = (const float*)d_in[4];
  const int*   nhist = (const int*)d_in[5];
  const int*   ths   = (const int*)d_in[6];
  const float* th0   = (const float*)d_in[7];
  const float* tc0   = (const float*)d_in[8];
  const float* Wtemb = (const float*)d_in[9];
  const float* btemb = (const float*)d_in[10];
  const float* Wiht  = (const float*)d_in[11];
  const float* Whht  = (const float*)d_in[12];
  const float* biht  = (const float*)d_in[13];
  const float* bhht  = (const float*)d_in[14];
  const float* Wtatt = (const float*)d_in[15];
  const float* btatt = (const float*)d_in[16];
  const float* nh0   = (const float*)d_in[17];
  const float* nc0   = (const float*)d_in[18];
  const float* Wnemb = (const float*)d_in[19];
  const float* bnemb = (const float*)d_in[20];
  const float* Wihn  = (const float*)d_in[21];
  const float* Whhn  = (const float*)d_in[22];
  const float* bihn  = (const float*)d_in[23];
  const float* bhhn  = (const float*)d_in[24];
  const float* Wnatt = (const float*)d_in[25];
  const float* bnatt = (const float*)d_in[26];
  const float* Wpred = (const float*)d_in[27];
  const float* bpred = (const float*)d_in[28];
  float* ws  = (float*)d_ws;
  float* out = (float*)d_out;

  const int ldsA = 157952;

  k_prep<<<259, 256, 0, stream>>>(Whhn, Whht, Wnemb, bnemb, Wihn, bihn, bhhn,
                                  Wtemb, btemb, Wiht, biht, bhht,
                                  trel, ths, th0, tc0, tpos, npos, nhist,
                                  Wtatt, btatt, Wnatt, bnatt, ws);
  k_phaseA<<<256, 256, ldsA, stream>>>(nh0, nc0, nrel, nhist, Wpred, ws);
  k_phaseB<<<1, 512, 0, stream>>>(img, tpos, npos, nh0, Wpred, bpred,
                                  Wtatt, btatt, Wnatt, bnatt, ws, out);
}